// Round 8
// baseline (209.509 us; speedup 1.0000x reference)
//
#include <hip/hip_runtime.h>
#include <hip/hip_bf16.h>
#include <stdint.h>
#include <stddef.h>

constexpr int Bc = 2;
constexpr int Sc = 4096;
constexpr int Dc = 512;
constexpr int Hc = 8;
constexpr int Wc = 32;

using bf16_t = __bf16;
typedef __attribute__((ext_vector_type(8))) __bf16 bf16x8;
typedef __attribute__((ext_vector_type(4))) float f32x4;

__device__ __forceinline__ void async_copy16(const void* g, void* l) {
    __builtin_amdgcn_global_load_lds(
        (const __attribute__((address_space(1))) void*)g,
        (__attribute__((address_space(3))) void*)l,
        16, 0, 0);
}

// Input dtype sniffer (measured round 7: fp32, flag=1). Kept for robustness.
__global__ void detect_dtype(const unsigned short* __restrict__ x16,
                             int* __restrict__ flag) {
    __shared__ int cnt;
    if (threadIdx.x == 0) cnt = 0;
    __syncthreads();
    int bad = 0;
    for (int i = threadIdx.x; i < 2048; i += 256) {
        unsigned e = (x16[i] >> 7) & 0xFFu;
        if (e == 0xFFu || e < 96u || e > 150u) bad++;
    }
    atomicAdd(&cnt, bad);
    __syncthreads();
    if (threadIdx.x == 0) *flag = (cnt > 100) ? 1 : 0;
}

__global__ void convert_kernel(const void* __restrict__ src,
                               bf16_t* __restrict__ dst, int n,
                               const int* __restrict__ flag) {
    const bool isf32 = (*flag != 0);
    const float*  fs = (const float*)src;
    const bf16_t* bs = (const bf16_t*)src;
    for (int i = blockIdx.x * blockDim.x + threadIdx.x; i < n;
         i += gridDim.x * blockDim.x)
        dst[i] = isf32 ? (bf16_t)fs[i] : bs[i];
}

// C = A @ B^T. A: (M x K) bf16 rm, B: (N x K) bf16 rm.
// nPerB>0: virtual B = [B0;B1;B2] each nPerB rows (fused QKV).
// F32OUT: write fp32 C (the harness output buffer is float*).
// Verified at thousands of random points (rounds 3-5).
template<int BM, int BN, int TM, int TN, bool F32OUT>
__global__ __launch_bounds__(256) void gemm_bt(
    const bf16_t* __restrict__ A, int lda,
    const bf16_t* __restrict__ B0, const bf16_t* __restrict__ B1,
    const bf16_t* __restrict__ B2, int ldb, int nPerB,
    void* __restrict__ C, int ldc, int K)
{
    constexpr int BK = 32;
    __shared__ __align__(1024) bf16_t Alds[BM * BK];
    __shared__ __align__(1024) bf16_t Blds[BN * BK];

    const int tid  = threadIdx.x;
    const int lane = tid & 63;
    const int wv   = tid >> 6;
    const int wm   = wv >> 1;
    const int wn   = wv & 1;
    const int r    = lane & 15;
    const int q4   = lane >> 4;

    const int blkM = blockIdx.x * BM;
    const int colC = blockIdx.y * BN;

    const bf16_t* Bp = B0;
    int nB = colC;
    if (nPerB > 0) {
        int wsel = colC / nPerB;
        nB = colC - wsel * nPerB;
        Bp = (wsel == 0) ? B0 : (wsel == 1) ? B1 : B2;
    }

    f32x4 acc[TM][TN];
    const f32x4 fzero = {0.f, 0.f, 0.f, 0.f};
    #pragma unroll
    for (int i = 0; i < TM; ++i)
        #pragma unroll
        for (int j = 0; j < TN; ++j) acc[i][j] = fzero;

    constexpr int A_LOADS = (BM * BK * 2) / (256 * 16);
    constexpr int B_LOADS = (BN * BK * 2) / (256 * 16);

    for (int kk = 0; kk < K; kk += BK) {
        __syncthreads();
        #pragma unroll
        for (int i = 0; i < A_LOADS; ++i) {
            int off  = i * 4096 + tid * 16;
            int row  = off >> 6;
            int colb = off & 63;
            const char* g = (const char*)A + ((size_t)(blkM + row) * lda + kk) * 2 + colb;
            async_copy16(g, (char*)Alds + off);
        }
        #pragma unroll
        for (int i = 0; i < B_LOADS; ++i) {
            int off  = i * 4096 + tid * 16;
            int row  = off >> 6;
            int colb = off & 63;
            const char* g = (const char*)Bp + ((size_t)(nB + row) * ldb + kk) * 2 + colb;
            async_copy16(g, (char*)Blds + off);
        }
        __syncthreads();

        bf16x8 af[TM], bfr[TN];
        #pragma unroll
        for (int mt = 0; mt < TM; ++mt)
            af[mt] = *(const bf16x8*)&Alds[(wm * TM * 16 + mt * 16 + r) * BK + q4 * 8];
        #pragma unroll
        for (int nt = 0; nt < TN; ++nt)
            bfr[nt] = *(const bf16x8*)&Blds[(wn * TN * 16 + nt * 16 + r) * BK + q4 * 8];

        #pragma unroll
        for (int mt = 0; mt < TM; ++mt)
            #pragma unroll
            for (int nt = 0; nt < TN; ++nt)
                acc[mt][nt] = __builtin_amdgcn_mfma_f32_16x16x32_bf16(
                    af[mt], bfr[nt], acc[mt][nt], 0, 0, 0);
    }

    // C/D layout: col = lane&15, row = q4*4 + reg (m89-verified).
    #pragma unroll
    for (int mt = 0; mt < TM; ++mt) {
        #pragma unroll
        for (int nt = 0; nt < TN; ++nt) {
            int rr0 = blkM + wm * TM * 16 + mt * 16 + q4 * 4;
            int cc  = colC + wn * TN * 16 + nt * 16 + r;
            #pragma unroll
            for (int i = 0; i < 4; ++i) {
                size_t o = (size_t)(rr0 + i) * ldc + cc;
                if constexpr (F32OUT) ((float*)C)[o]  = acc[mt][nt][i];
                else                  ((bf16_t*)C)[o] = (bf16_t)acc[mt][nt][i];
            }
        }
    }
}

// Neighbor attention (verified vs scalar recompute, round 5).
// One wave per (b,h,s). lane pairs compute scores; lane=d for V accumulate.
// QKV rows: [Q(512)|K(512)|V(512)] bf16.
__global__ __launch_bounds__(256) void attn_boring(
    const bf16_t* __restrict__ QKV,
    const int*    __restrict__ nidx,
    bf16_t*       __restrict__ attn_out)
{
    __shared__ float sc_lds[4][32];
    const int lane = threadIdx.x & 63;
    const int wv   = threadIdx.x >> 6;
    const int wg   = blockIdx.x * 4 + wv;          // 0..65535
    const int s = wg & (Sc - 1);
    const int h = (wg >> 12) & (Hc - 1);
    const int b = wg >> 15;
    const size_t row = (size_t)b * Sc + s;

    const bf16_t* Qr = QKV + row * 1536 + h * 64;
    const bf16_t* Kb = QKV + (size_t)b * Sc * 1536 + 512 + h * 64;
    const bf16_t* Vb = Kb + 512;

    {
        const int w  = lane >> 1;
        const int d0 = (lane & 1) * 32;
        const int t  = nidx[s * Wc + w];
        float part = 0.f;
        for (int j = 0; j < 32; ++j)
            part += (float)Qr[d0 + j] * (float)Kb[(size_t)t * 1536 + d0 + j];
        part += __shfl_xor(part, 1);
        if ((lane & 1) == 0) sc_lds[wv][w] = part * 0.125f;
    }
    __syncthreads();

    float e[32];
    float mx = -1e30f, sum = 0.f;
    for (int w = 0; w < 32; ++w) mx = fmaxf(mx, sc_lds[wv][w]);
    for (int w = 0; w < 32; ++w) { e[w] = __expf(sc_lds[wv][w] - mx); sum += e[w]; }
    const float inv = 1.f / sum;

    float acc = 0.f;
    for (int w = 0; w < 32; ++w) {
        int t = nidx[s * Wc + w];
        acc = fmaf(e[w] * inv, (float)Vb[(size_t)t * 1536 + lane], acc);
    }
    attn_out[row * 512 + h * 64 + lane] = (bf16_t)acc;
}

extern "C" void kernel_launch(void* const* d_in, const int* in_sizes, int n_in,
                              void* d_out, int out_size, void* d_ws, size_t ws_size,
                              hipStream_t stream) {
    (void)in_sizes; (void)n_in; (void)out_size; (void)ws_size;
    const int* nidx = (const int*)d_in[5];
    const int M = Bc * Sc;                        // 8192
    float* out = (float*)d_out;                   // fp32 output (round-7 finding)

    char* w = (char*)d_ws;
    int*    flag = (int*)w;
    bf16_t* xc   = (bf16_t*)(w + 256);            // 4,194,304 el (8 MB)
    bf16_t* Wqc  = xc  + 4194304;                 // 262,144 each (0.5 MB)
    bf16_t* Wkc  = Wqc + 262144;
    bf16_t* Wvc  = Wkc + 262144;
    bf16_t* Woc  = Wvc + 262144;
    bf16_t* qkv  = Woc + 262144;                  // 12,582,912 el (24 MB)
    bf16_t* attnS = xc;                           // reuse x-buffer after GEMM1
                                                  // total ws: ~34 MB (< 35 MB floor)

    detect_dtype<<<1, 256, 0, stream>>>((const unsigned short*)d_in[0], flag);
    convert_kernel<<<1024, 256, 0, stream>>>(d_in[0], xc,  4194304, flag);
    convert_kernel<<<256,  256, 0, stream>>>(d_in[1], Wqc, 262144,  flag);
    convert_kernel<<<256,  256, 0, stream>>>(d_in[2], Wkc, 262144,  flag);
    convert_kernel<<<256,  256, 0, stream>>>(d_in[3], Wvc, 262144,  flag);
    convert_kernel<<<256,  256, 0, stream>>>(d_in[4], Woc, 262144,  flag);

    // Fused QKV projection: M=8192, N=1536, K=512 (bf16 out to ws).
    gemm_bt<128, 128, 4, 4, false><<<dim3(M / 128, 1536 / 128), 256, 0, stream>>>(
        xc, Dc, Wqc, Wkc, Wvc, Dc, 512, qkv, 1536, Dc);

    // Neighbor attention: one wave per (b,h,s); writes bf16 attnS (over xc).
    attn_boring<<<(Bc * Hc * Sc) / 4, 256, 0, stream>>>(qkv, nidx, attnS);

    // Output projection: M=8192, N=512, K=512 -> fp32 d_out.
    gemm_bt<64, 64, 2, 2, true><<<dim3(M / 64, 512 / 64), 256, 0, stream>>>(
        attnS, 512, Woc, Woc, Woc, 512, 0, out, Dc, Dc);
}

// Round 9
// 158.051 us; speedup vs baseline: 1.3256x; 1.3256x over previous
//
#include <hip/hip_runtime.h>
#include <hip/hip_bf16.h>
#include <stdint.h>
#include <stddef.h>

constexpr int Bc = 2;
constexpr int Sc = 4096;
constexpr int Dc = 512;
constexpr int Hc = 8;
constexpr int Wc = 32;

using bf16_t = __bf16;
typedef __attribute__((ext_vector_type(8))) __bf16 bf16x8;
typedef __attribute__((ext_vector_type(4))) __bf16 bf16x4;
typedef __attribute__((ext_vector_type(4))) float f32x4;

__device__ __forceinline__ void async_copy16(const void* g, void* l) {
    __builtin_amdgcn_global_load_lds(
        (const __attribute__((address_space(1))) void*)g,
        (__attribute__((address_space(3))) void*)l,
        16, 0, 0);
}

// Input dtype sniffer (measured round 7: fp32). Kept for robustness.
__global__ void detect_dtype(const unsigned short* __restrict__ x16,
                             int* __restrict__ flag) {
    __shared__ int cnt;
    if (threadIdx.x == 0) cnt = 0;
    __syncthreads();
    int bad = 0;
    for (int i = threadIdx.x; i < 2048; i += 256) {
        unsigned e = (x16[i] >> 7) & 0xFFu;
        if (e == 0xFFu || e < 96u || e > 150u) bad++;
    }
    atomicAdd(&cnt, bad);
    __syncthreads();
    if (threadIdx.x == 0) *flag = (cnt > 100) ? 1 : 0;
}

// x convert: 4 elems/thread, vectorized fp32 path. grid 4096 x 256.
__global__ void convert_x(const void* __restrict__ src, bf16_t* __restrict__ dst,
                          const int* __restrict__ flag) {
    const int i = (blockIdx.x * 256 + threadIdx.x) * 4;
    if (*flag) {
        const float4 v = *(const float4*)((const float*)src + i);
        bf16x4 o; o[0] = (bf16_t)v.x; o[1] = (bf16_t)v.y;
        o[2] = (bf16_t)v.z; o[3] = (bf16_t)v.w;
        *(bf16x4*)(dst + i) = o;
    } else {
        *(bf16x4*)(dst + i) = *(const bf16x4*)((const bf16_t*)src + i);
    }
}

// All four weight tensors in one launch. grid 1024 x 256 (256 blocks each).
__global__ void convert_w4(const void* __restrict__ s0, const void* __restrict__ s1,
                           const void* __restrict__ s2, const void* __restrict__ s3,
                           bf16_t* __restrict__ d0, bf16_t* __restrict__ d1,
                           bf16_t* __restrict__ d2, bf16_t* __restrict__ d3,
                           const int* __restrict__ flag) {
    const int which = blockIdx.x >> 8;
    const void* s = (which == 0) ? s0 : (which == 1) ? s1 : (which == 2) ? s2 : s3;
    bf16_t*    d  = (which == 0) ? d0 : (which == 1) ? d1 : (which == 2) ? d2 : d3;
    const int i = ((blockIdx.x & 255) * 256 + threadIdx.x) * 4;
    if (*flag) {
        const float4 v = *(const float4*)((const float*)s + i);
        bf16x4 o; o[0] = (bf16_t)v.x; o[1] = (bf16_t)v.y;
        o[2] = (bf16_t)v.z; o[3] = (bf16_t)v.w;
        *(bf16x4*)(d + i) = o;
    } else {
        *(bf16x4*)(d + i) = *(const bf16x4*)((const bf16_t*)s + i);
    }
}

// C = A @ B^T (verified rounds 3-8). nPerB>0: virtual B=[B0;B1;B2].
template<int BM, int BN, int TM, int TN, bool F32OUT>
__global__ __launch_bounds__(256) void gemm_bt(
    const bf16_t* __restrict__ A, int lda,
    const bf16_t* __restrict__ B0, const bf16_t* __restrict__ B1,
    const bf16_t* __restrict__ B2, int ldb, int nPerB,
    void* __restrict__ C, int ldc, int K)
{
    constexpr int BK = 32;
    __shared__ __align__(1024) bf16_t Alds[BM * BK];
    __shared__ __align__(1024) bf16_t Blds[BN * BK];

    const int tid  = threadIdx.x;
    const int lane = tid & 63;
    const int wv   = tid >> 6;
    const int wm   = wv >> 1;
    const int wn   = wv & 1;
    const int r    = lane & 15;
    const int q4   = lane >> 4;

    const int blkM = blockIdx.x * BM;
    const int colC = blockIdx.y * BN;

    const bf16_t* Bp = B0;
    int nB = colC;
    if (nPerB > 0) {
        int wsel = colC / nPerB;
        nB = colC - wsel * nPerB;
        Bp = (wsel == 0) ? B0 : (wsel == 1) ? B1 : B2;
    }

    f32x4 acc[TM][TN];
    const f32x4 fzero = {0.f, 0.f, 0.f, 0.f};
    #pragma unroll
    for (int i = 0; i < TM; ++i)
        #pragma unroll
        for (int j = 0; j < TN; ++j) acc[i][j] = fzero;

    constexpr int A_LOADS = (BM * BK * 2) / (256 * 16);
    constexpr int B_LOADS = (BN * BK * 2) / (256 * 16);

    for (int kk = 0; kk < K; kk += BK) {
        __syncthreads();
        #pragma unroll
        for (int i = 0; i < A_LOADS; ++i) {
            int off  = i * 4096 + tid * 16;
            int row  = off >> 6;
            int colb = off & 63;
            const char* g = (const char*)A + ((size_t)(blkM + row) * lda + kk) * 2 + colb;
            async_copy16(g, (char*)Alds + off);
        }
        #pragma unroll
        for (int i = 0; i < B_LOADS; ++i) {
            int off  = i * 4096 + tid * 16;
            int row  = off >> 6;
            int colb = off & 63;
            const char* g = (const char*)Bp + ((size_t)(nB + row) * ldb + kk) * 2 + colb;
            async_copy16(g, (char*)Blds + off);
        }
        __syncthreads();

        bf16x8 af[TM], bfr[TN];
        #pragma unroll
        for (int mt = 0; mt < TM; ++mt)
            af[mt] = *(const bf16x8*)&Alds[(wm * TM * 16 + mt * 16 + r) * BK + q4 * 8];
        #pragma unroll
        for (int nt = 0; nt < TN; ++nt)
            bfr[nt] = *(const bf16x8*)&Blds[(wn * TN * 16 + nt * 16 + r) * BK + q4 * 8];

        #pragma unroll
        for (int mt = 0; mt < TM; ++mt)
            #pragma unroll
            for (int nt = 0; nt < TN; ++nt)
                acc[mt][nt] = __builtin_amdgcn_mfma_f32_16x16x32_bf16(
                    af[mt], bfr[nt], acc[mt][nt], 0, 0, 0);
    }

    #pragma unroll
    for (int mt = 0; mt < TM; ++mt) {
        #pragma unroll
        for (int nt = 0; nt < TN; ++nt) {
            int rr0 = blkM + wm * TM * 16 + mt * 16 + q4 * 4;
            int cc  = colC + wn * TN * 16 + nt * 16 + r;
            #pragma unroll
            for (int i = 0; i < 4; ++i) {
                size_t o = (size_t)(rr0 + i) * ldc + cc;
                if constexpr (F32OUT) ((float*)C)[o]  = acc[mt][nt][i];
                else                  ((bf16_t*)C)[o] = (bf16_t)acc[mt][nt][i];
            }
        }
    }
}

// Vectorized neighbor attention. One wave per (b,h,s).
// Phase 1: lane pair (w = lane>>1, half = lane&1) computes q.k via 4x bf16x8
//          vector loads per operand; butterfly softmax in registers.
// Phase 3: lane = d; (byte-offset, weight) pairs staged in LDS.
__global__ __launch_bounds__(256) void attn_fast(
    const bf16_t* __restrict__ QKV,
    const int*    __restrict__ nidx,
    bf16_t*       __restrict__ attn_out)
{
    __shared__ float wa_lds[4][64];                // 32 x (offset_bits, weight)
    const int lane = threadIdx.x & 63;
    const int wv   = threadIdx.x >> 6;

    // XCD swizzle: contiguous s-range per XCD for gather L2 locality.
    const int bi  = blockIdx.x;
    const int blk = (bi & 7) * 2048 + (bi >> 3);
    const int wg  = blk * 4 + wv;                  // ((b*8+h)<<12) + s
    const int s = wg & (Sc - 1);
    const int h = (wg >> 12) & (Hc - 1);
    const int b = wg >> 15;
    const size_t row = (size_t)b * Sc + s;

    const int w    = lane >> 1;
    const int half = lane & 1;
    const int t    = nidx[s * Wc + w];

    const char* qkvB  = (const char*)QKV;
    const char* Qptr  = qkvB + row * 3072 + h * 128 + half * 64;
    const char* Kptr  = qkvB + ((size_t)b * Sc + t) * 3072 + 1024 + h * 128 + half * 64;

    bf16x8 q8[4], k8[4];
    #pragma unroll
    for (int i = 0; i < 4; ++i) {
        q8[i] = *(const bf16x8*)(Qptr + 16 * i);
        k8[i] = *(const bf16x8*)(Kptr + 16 * i);
    }
    float p = 0.f;
    #pragma unroll
    for (int i = 0; i < 4; ++i)
        #pragma unroll
        for (int j = 0; j < 8; ++j)
            p += (float)q8[i][j] * (float)k8[i][j];
    p += __shfl_xor(p, 1);                         // full 64-dot in both pair lanes
    p *= 0.125f;                                   // 1/sqrt(64)

    // Butterfly softmax over the 32 lane-pairs (pairs hold identical p).
    float mx = p;
    #pragma unroll
    for (int m = 2; m <= 32; m <<= 1) mx = fmaxf(mx, __shfl_xor(mx, m));
    const float e = __expf(p - mx);
    float sum = e;
    #pragma unroll
    for (int m = 2; m <= 32; m <<= 1) sum += __shfl_xor(sum, m);
    const float a = e / sum;

    if (half == 0) {
        wa_lds[wv][2 * w]     = __int_as_float(t * 3072);
        wa_lds[wv][2 * w + 1] = a;
    }
    __syncthreads();

    // Phase 3: lane = d. Wave-uniform base + 32-bit voffset.
    const char* VbaseU = qkvB + (size_t)b * Sc * 3072 + 2048 + h * 128 + lane * 2;
    float acc = 0.f;
    #pragma unroll
    for (int w4 = 0; w4 < 8; ++w4) {
        const float4 c0 = *(const float4*)&wa_lds[wv][8 * w4];
        const float4 c1 = *(const float4*)&wa_lds[wv][8 * w4 + 4];
        acc = fmaf(c0.y, (float)*(const bf16_t*)(VbaseU + __float_as_int(c0.x)), acc);
        acc = fmaf(c0.w, (float)*(const bf16_t*)(VbaseU + __float_as_int(c0.z)), acc);
        acc = fmaf(c1.y, (float)*(const bf16_t*)(VbaseU + __float_as_int(c1.x)), acc);
        acc = fmaf(c1.w, (float)*(const bf16_t*)(VbaseU + __float_as_int(c1.z)), acc);
    }
    attn_out[row * 512 + h * 64 + lane] = (bf16_t)acc;
}

extern "C" void kernel_launch(void* const* d_in, const int* in_sizes, int n_in,
                              void* d_out, int out_size, void* d_ws, size_t ws_size,
                              hipStream_t stream) {
    (void)in_sizes; (void)n_in; (void)out_size; (void)ws_size;
    const int* nidx = (const int*)d_in[5];
    const int M = Bc * Sc;                        // 8192
    float* out = (float*)d_out;                   // fp32 output (round-7 finding)

    char* w = (char*)d_ws;
    int*    flag = (int*)w;
    bf16_t* xc   = (bf16_t*)(w + 256);            // 8 MB
    bf16_t* Wqc  = xc  + 4194304;                 // 0.5 MB each
    bf16_t* Wkc  = Wqc + 262144;
    bf16_t* Wvc  = Wkc + 262144;
    bf16_t* Woc  = Wvc + 262144;
    bf16_t* qkv  = Woc + 262144;                  // 24 MB
    bf16_t* attnS = xc;                           // reuse x-buffer after GEMM1

    detect_dtype<<<1, 256, 0, stream>>>((const unsigned short*)d_in[0], flag);
    convert_x<<<4096, 256, 0, stream>>>(d_in[0], xc, flag);
    convert_w4<<<1024, 256, 0, stream>>>(d_in[1], d_in[2], d_in[3], d_in[4],
                                         Wqc, Wkc, Wvc, Woc, flag);

    // Fused QKV projection: M=8192, N=1536, K=512 (bf16 out).
    gemm_bt<128, 128, 4, 4, false><<<dim3(M / 128, 1536 / 128), 256, 0, stream>>>(
        xc, Dc, Wqc, Wkc, Wvc, Dc, 512, qkv, 1536, Dc);

    // Neighbor attention.
    attn_fast<<<(Bc * Hc * Sc) / 4, 256, 0, stream>>>(qkv, nidx, attnS);

    // Output projection: M=8192, N=512, K=512 -> fp32 d_out.
    gemm_bt<64, 64, 2, 2, true><<<dim3(M / 64, 512 / 64), 256, 0, stream>>>(
        attnS, 512, Woc, Woc, Woc, 512, 0, out, Dc, Dc);
}

// Round 10
// 148.658 us; speedup vs baseline: 1.4093x; 1.0632x over previous
//
#include <hip/hip_runtime.h>
#include <hip/hip_bf16.h>
#include <stdint.h>
#include <stddef.h>

constexpr int Bc = 2;
constexpr int Sc = 4096;
constexpr int Dc = 512;
constexpr int Hc = 8;
constexpr int Wc = 32;

using bf16_t = __bf16;
typedef __attribute__((ext_vector_type(8))) __bf16 bf16x8;
typedef __attribute__((ext_vector_type(4))) __bf16 bf16x4;
typedef __attribute__((ext_vector_type(2))) __bf16 bf16x2;
typedef __attribute__((ext_vector_type(4))) float f32x4;

__device__ __forceinline__ void async_copy16(const void* g, void* l) {
    __builtin_amdgcn_global_load_lds(
        (const __attribute__((address_space(1))) void*)g,
        (__attribute__((address_space(3))) void*)l,
        16, 0, 0);
}

// All input conversions in one launch (inputs are fp32 — measured round 7).
// Blocks 0..4095: x (4 elem/thread). Blocks 4096..5119: the 4 weights.
__global__ void convert_all(const float* __restrict__ x,
                            const float* __restrict__ wq, const float* __restrict__ wk,
                            const float* __restrict__ wv, const float* __restrict__ wo,
                            bf16_t* __restrict__ xc, bf16_t* __restrict__ dq,
                            bf16_t* __restrict__ dk, bf16_t* __restrict__ dv,
                            bf16_t* __restrict__ dwo) {
    const int blk = blockIdx.x;
    const float* s; bf16_t* d; int base;
    if (blk < 4096) { s = x; d = xc; base = blk * 1024; }
    else {
        const int r = blk - 4096, which = r >> 8;
        s = (which == 0) ? wq : (which == 1) ? wk : (which == 2) ? wv : wo;
        d = (which == 0) ? dq : (which == 1) ? dk : (which == 2) ? dv : dwo;
        base = (r & 255) * 1024;
    }
    const int i = base + threadIdx.x * 4;
    const float4 v = *(const float4*)(s + i);
    bf16x4 o; o[0] = (bf16_t)v.x; o[1] = (bf16_t)v.y;
    o[2] = (bf16_t)v.z; o[3] = (bf16_t)v.w;
    *(bf16x4*)(d + i) = o;
}

// C = A @ B^T (verified rounds 3-9). nPerB>0: virtual B=[B0;B1;B2].
template<int BM, int BN, int TM, int TN, bool F32OUT>
__global__ __launch_bounds__(256) void gemm_bt(
    const bf16_t* __restrict__ A, int lda,
    const bf16_t* __restrict__ B0, const bf16_t* __restrict__ B1,
    const bf16_t* __restrict__ B2, int ldb, int nPerB,
    void* __restrict__ C, int ldc, int K)
{
    constexpr int BK = 32;
    __shared__ __align__(1024) bf16_t Alds[BM * BK];
    __shared__ __align__(1024) bf16_t Blds[BN * BK];

    const int tid  = threadIdx.x;
    const int lane = tid & 63;
    const int wv   = tid >> 6;
    const int wm   = wv >> 1;
    const int wn   = wv & 1;
    const int r    = lane & 15;
    const int q4   = lane >> 4;

    const int blkM = blockIdx.x * BM;
    const int colC = blockIdx.y * BN;

    const bf16_t* Bp = B0;
    int nB = colC;
    if (nPerB > 0) {
        int wsel = colC / nPerB;
        nB = colC - wsel * nPerB;
        Bp = (wsel == 0) ? B0 : (wsel == 1) ? B1 : B2;
    }

    f32x4 acc[TM][TN];
    const f32x4 fzero = {0.f, 0.f, 0.f, 0.f};
    #pragma unroll
    for (int i = 0; i < TM; ++i)
        #pragma unroll
        for (int j = 0; j < TN; ++j) acc[i][j] = fzero;

    constexpr int A_LOADS = (BM * BK * 2) / (256 * 16);
    constexpr int B_LOADS = (BN * BK * 2) / (256 * 16);

    for (int kk = 0; kk < K; kk += BK) {
        __syncthreads();
        #pragma unroll
        for (int i = 0; i < A_LOADS; ++i) {
            int off  = i * 4096 + tid * 16;
            int row  = off >> 6;
            int colb = off & 63;
            const char* g = (const char*)A + ((size_t)(blkM + row) * lda + kk) * 2 + colb;
            async_copy16(g, (char*)Alds + off);
        }
        #pragma unroll
        for (int i = 0; i < B_LOADS; ++i) {
            int off  = i * 4096 + tid * 16;
            int row  = off >> 6;
            int colb = off & 63;
            const char* g = (const char*)Bp + ((size_t)(nB + row) * ldb + kk) * 2 + colb;
            async_copy16(g, (char*)Blds + off);
        }
        __syncthreads();

        bf16x8 af[TM], bfr[TN];
        #pragma unroll
        for (int mt = 0; mt < TM; ++mt)
            af[mt] = *(const bf16x8*)&Alds[(wm * TM * 16 + mt * 16 + r) * BK + q4 * 8];
        #pragma unroll
        for (int nt = 0; nt < TN; ++nt)
            bfr[nt] = *(const bf16x8*)&Blds[(wn * TN * 16 + nt * 16 + r) * BK + q4 * 8];

        #pragma unroll
        for (int mt = 0; mt < TM; ++mt)
            #pragma unroll
            for (int nt = 0; nt < TN; ++nt)
                acc[mt][nt] = __builtin_amdgcn_mfma_f32_16x16x32_bf16(
                    af[mt], bfr[nt], acc[mt][nt], 0, 0, 0);
    }

    #pragma unroll
    for (int mt = 0; mt < TM; ++mt) {
        #pragma unroll
        for (int nt = 0; nt < TN; ++nt) {
            int rr0 = blkM + wm * TM * 16 + mt * 16 + q4 * 4;
            int cc  = colC + wn * TN * 16 + nt * 16 + r;
            #pragma unroll
            for (int i = 0; i < 4; ++i) {
                size_t o = (size_t)(rr0 + i) * ldc + cc;
                if constexpr (F32OUT) ((float*)C)[o]  = acc[mt][nt][i];
                else                  ((bf16_t*)C)[o] = (bf16_t)acc[mt][nt][i];
            }
        }
    }
}

// Neighbor attention, one wave per (b,h,s).
// Phase 1: lane pair (w = lane>>1, half = lane&1): q.k via 4x bf16x8 loads,
//          butterfly softmax in registers (verified round 9).
// Phase 3: lane = (nh = lane>>5, d2 = lane&31): each lane accumulates dims
//          {2*d2, 2*d2+1} over 16 neighbors via dword V loads (2 bf16 each),
//          then a 1-shuffle merge across nh and a packed bf16x2 store.
__global__ __launch_bounds__(256) void attn_fast(
    const bf16_t* __restrict__ QKV,
    const int*    __restrict__ nidx,
    bf16_t*       __restrict__ attn_out)
{
    __shared__ __align__(16) float wa_lds[4][64];  // 32 x (off_bits, weight)
    const int lane = threadIdx.x & 63;
    const int wv   = threadIdx.x >> 6;

    // XCD swizzle: contiguous s-range per XCD for gather L2 locality.
    const int bi  = blockIdx.x;
    const int blk = (bi & 7) * 2048 + (bi >> 3);
    const int wg  = blk * 4 + wv;                  // ((b*8+h)<<12) + s
    const int s = wg & (Sc - 1);
    const int h = (wg >> 12) & (Hc - 1);
    const int b = wg >> 15;
    const size_t row = (size_t)b * Sc + s;

    const int w    = lane >> 1;
    const int half = lane & 1;
    const int t    = nidx[s * Wc + w];

    const char* qkvB = (const char*)QKV;
    const char* Qptr = qkvB + row * 3072 + h * 128 + half * 64;
    const char* Kptr = qkvB + ((size_t)b * Sc + t) * 3072 + 1024 + h * 128 + half * 64;

    bf16x8 q8[4], k8[4];
    #pragma unroll
    for (int i = 0; i < 4; ++i) {
        q8[i] = *(const bf16x8*)(Qptr + 16 * i);
        k8[i] = *(const bf16x8*)(Kptr + 16 * i);
    }
    float p = 0.f;
    #pragma unroll
    for (int i = 0; i < 4; ++i)
        #pragma unroll
        for (int j = 0; j < 8; ++j)
            p += (float)q8[i][j] * (float)k8[i][j];
    p += __shfl_xor(p, 1);                         // full 64-dot in both pair lanes
    p *= 0.125f;                                   // 1/sqrt(64)

    // Butterfly softmax over the 32 lane-pairs.
    float mx = p;
    #pragma unroll
    for (int m = 2; m <= 32; m <<= 1) mx = fmaxf(mx, __shfl_xor(mx, m));
    const float e = __expf(p - mx);
    float sum = e;
    #pragma unroll
    for (int m = 2; m <= 32; m <<= 1) sum += __shfl_xor(sum, m);
    const float a = e / sum;

    if (half == 0) {
        wa_lds[wv][2 * w]     = __int_as_float(t * 3072);
        wa_lds[wv][2 * w + 1] = a;
    }
    __syncthreads();

    // Phase 3. Wave-uniform 64-bit V base; 32-bit per-lane voffset.
    const int d2 = lane & 31;                      // dims 2*d2, 2*d2+1
    const int nh = lane >> 5;                      // neighbors nh*16 .. nh*16+15
    const float* chunkp = &wa_lds[wv][nh * 32];
    const char* Vb = qkvB + (size_t)b * Sc * 3072 + 2048 + h * 128;
    const int dk = d2 * 4;

    float acc0 = 0.f, acc1 = 0.f;
    #pragma unroll
    for (int j = 0; j < 8; ++j) {
        const float4 c = *(const float4*)(chunkp + 4 * j);
        {
            const unsigned v = *(const unsigned*)(Vb + __float_as_int(c.x) + dk);
            acc0 = fmaf(c.y, __uint_as_float(v << 16), acc0);
            acc1 = fmaf(c.y, __uint_as_float(v & 0xffff0000u), acc1);
        }
        {
            const unsigned v = *(const unsigned*)(Vb + __float_as_int(c.z) + dk);
            acc0 = fmaf(c.w, __uint_as_float(v << 16), acc0);
            acc1 = fmaf(c.w, __uint_as_float(v & 0xffff0000u), acc1);
        }
    }
    acc0 += __shfl_xor(acc0, 32);
    acc1 += __shfl_xor(acc1, 32);
    if (nh == 0) {
        bf16x2 pr; pr[0] = (bf16_t)acc0; pr[1] = (bf16_t)acc1;
        *(bf16x2*)((char*)attn_out + row * 1024 + h * 128 + dk) = pr;
    }
}

extern "C" void kernel_launch(void* const* d_in, const int* in_sizes, int n_in,
                              void* d_out, int out_size, void* d_ws, size_t ws_size,
                              hipStream_t stream) {
    (void)in_sizes; (void)n_in; (void)out_size; (void)ws_size;
    const int* nidx = (const int*)d_in[5];
    const int M = Bc * Sc;                        // 8192
    float* out = (float*)d_out;                   // fp32 output (round-7 finding)

    char* w = (char*)d_ws;
    bf16_t* xc   = (bf16_t*)(w + 256);            // 8 MB
    bf16_t* Wqc  = xc  + 4194304;                 // 0.5 MB each
    bf16_t* Wkc  = Wqc + 262144;
    bf16_t* Wvc  = Wkc + 262144;
    bf16_t* Woc  = Wvc + 262144;
    bf16_t* qkv  = Woc + 262144;                  // 24 MB
    bf16_t* attnS = xc;                           // reuse x-buffer after GEMM1

    convert_all<<<5120, 256, 0, stream>>>(
        (const float*)d_in[0], (const float*)d_in[1], (const float*)d_in[2],
        (const float*)d_in[3], (const float*)d_in[4],
        xc, Wqc, Wkc, Wvc, Woc);

    // Fused QKV projection: M=8192, N=1536, K=512 (bf16 out).
    gemm_bt<128, 128, 4, 4, false><<<dim3(M / 128, 1536 / 128), 256, 0, stream>>>(
        xc, Dc, Wqc, Wkc, Wvc, Dc, 512, qkv, 1536, Dc);

    // Neighbor attention.
    attn_fast<<<(Bc * Hc * Sc) / 4, 256, 0, stream>>>(qkv, nidx, attnS);

    // Output projection: M=8192, N=512, K=512 -> fp32 d_out.
    gemm_bt<128, 64, 4, 2, true><<<dim3(M / 128, 512 / 64), 256, 0, stream>>>(
        attnS, 512, Woc, Woc, Woc, 512, 0, out, Dc, Dc);
}